// Round 2
// baseline (932.924 us; speedup 1.0000x reference)
//
#include <hip/hip_runtime.h>
#include <cstdint>

#define TT 50
#define II 5
#define PRED 12
#define SAMP 32   // samples per block
#define NS 2      // 16-sample subtiles per block

typedef _Float16 f16;
typedef _Float16 f16x8 __attribute__((ext_vector_type(8)));
typedef float f32x4 __attribute__((ext_vector_type(4)));

// ---------------- prep: fragment-ordered f16 weights (both phases fused) ----
// per phase: flat f = (((wg*5 + kc)*4 + q)*16 + c)*8 + j, wg = w*4+gsub
// Wcat[g][k]: g = gsub*128 + w*16 + c, k = kc*32 + q*8 + j
//   k<128 -> Whh[g][k]; 128..132 -> Wih[g][k-128]; k==133 -> bih[g]+bhh[g]; else 0
__global__ void prep_weights(const float* __restrict__ eWih, const float* __restrict__ eWhh,
                             const float* __restrict__ ebih, const float* __restrict__ ebhh,
                             const float* __restrict__ dWih, const float* __restrict__ dWhh,
                             const float* __restrict__ dbih, const float* __restrict__ dbhh,
                             f16* __restrict__ outw) {
    int f = blockIdx.x * 256 + threadIdx.x;
    if (f >= 2 * 81920) return;
    int ph = (f >= 81920);
    int fl = f - ph * 81920;
    const float* Wih = ph ? dWih : eWih;
    const float* Whh = ph ? dWhh : eWhh;
    const float* bih = ph ? dbih : ebih;
    const float* bhh = ph ? dbhh : ebhh;
    int j  = fl & 7;
    int c  = (fl >> 3) & 15;
    int q  = (fl >> 7) & 3;
    int t2 = fl >> 9;             // 0..159
    int kc = t2 % 5;
    int wg = t2 / 5;              // 0..31
    int w = wg >> 2, gsub = wg & 3;
    int g = gsub * 128 + w * 16 + c;
    int k = kc * 32 + q * 8 + j;
    float v;
    if (k < 128)       v = Whh[g * 128 + k];
    else if (k < 133)  v = Wih[g * 5 + (k - 128)];
    else if (k == 133) v = bih[g] + bhh[g];
    else               v = 0.f;
    outw[f] = (f16)v;
}

#define K1 1.4426950408889634f
#define K2 2.8853900817779268f

// ---------------- persistent LSTM kernel ----------------
// 512 blocks x 512 threads; 32 samples/block; double-buffered state,
// row = 256 f16 (512 B, 32 chunks), chunk swizzle phys = logical ^ (2*(s&15)).
// Fused-rational cell update: 5 exp + 2 rcp per cell.
__global__ __launch_bounds__(512, 4)
void lstm_kernel(const float* __restrict__ x,
                 const f16* __restrict__ wfrag,      // [2][81920]
                 const float* __restrict__ linW, const float* __restrict__ linB,
                 float* __restrict__ out) {
    __shared__ __align__(16) unsigned char state[2][SAMP * 512];
    __shared__ float predpart[8][SAMP][2];

    const int tid  = threadIdx.x;
    const int lane = tid & 63;
    const int w    = tid >> 6;       // wave 0..7
    const int q    = lane >> 4;      // 0..3
    const int cl   = lane & 15;      // 0..15
    const int s0   = blockIdx.x * SAMP;
    const int jb   = w * 16 + q * 4; // this lane's hidden-j base
    const int physh = ((jb >> 3) ^ (2 * cl)) & 31;   // h-write chunk
    const int hoff  = (jb & 7) * 2;                  // 0 or 8 bytes

    // encoder weight fragments -> registers (80 VGPR)
    f16x8 wr[4][5];
    {
        const f16x8* wp = (const f16x8*)wfrag;
        #pragma unroll
        for (int gs = 0; gs < 4; ++gs) {
            #pragma unroll
            for (int kc = 0; kc < 5; ++kc)
                wr[gs][kc] = wp[((w * 4 + gs) * 5 + kc) * 64 + lane];
        }
    }
    // zero both state buffers (h0 = 0, zero pad chunks)
    {
        uint32_t* sp = (uint32_t*)state;
        #pragma unroll
        for (int r = 0; r < 16; ++r) sp[tid + r * 512] = 0u;
    }
    float creg[NS][4];
    #pragma unroll
    for (int a = 0; a < NS; ++a)
        #pragma unroll
        for (int b = 0; b < 4; ++b) creg[a][b] = 0.f;

    __syncthreads();
    // x_0 chunk (logical chunk 16) into buf0
    if (tid < SAMP) {
        const float* xr = x + (size_t)(s0 + tid) * (TT * II);
        union { f16 h[8]; uint4 u; } pk;
        pk.h[0] = (f16)xr[0]; pk.h[1] = (f16)xr[1]; pk.h[2] = (f16)xr[2];
        pk.h[3] = (f16)xr[3]; pk.h[4] = (f16)xr[4];
        pk.h[5] = (f16)1.f; pk.h[6] = (f16)0.f; pk.h[7] = (f16)0.f;
        int phys = 16 ^ (2 * (tid & 15));
        *(uint4*)(&state[0][0] + tid * 512 + phys * 16) = pk.u;
    }
    __syncthreads();

    f32x4 zero4 = {0.f, 0.f, 0.f, 0.f};

    // ===================== encoder (1 barrier/step, double-buffered) ========
    #pragma unroll 1
    for (int t = 0; t < TT; ++t) {
        unsigned char* cur = &state[t & 1][0];
        unsigned char* nxt = &state[(t + 1) & 1][0];
        // prefetch next x (t=49 re-reads x_49 == dec_in0, since
        // dec_in0 = [x49_vel(2), x49_static(3)] = x_49 exactly)
        float xv0 = 0, xv1 = 0, xv2 = 0, xv3 = 0, xv4 = 0;
        if (tid < SAMP) {
            int tn = (t < TT - 1) ? t + 1 : TT - 1;
            const float* xr = x + (size_t)(s0 + tid) * (TT * II) + tn * II;
            xv0 = xr[0]; xv1 = xr[1]; xv2 = xr[2]; xv3 = xr[3]; xv4 = xr[4];
        }
        f32x4 acc[4][NS];
        #pragma unroll
        for (int gs = 0; gs < 4; ++gs)
            #pragma unroll
            for (int ns = 0; ns < NS; ++ns) acc[gs][ns] = zero4;

        #pragma unroll
        for (int ns = 0; ns < NS; ++ns) {
            const int srow = ns * 16 + cl;
            #pragma unroll
            for (int kc = 0; kc < 5; ++kc) {
                const int phys = (kc * 4 + q) ^ (2 * cl);
                f16x8 bf = *(const f16x8*)(cur + srow * 512 + phys * 16);
                acc[0][ns] = __builtin_amdgcn_mfma_f32_16x16x32_f16(wr[0][kc], bf, acc[0][ns], 0, 0, 0);
                acc[1][ns] = __builtin_amdgcn_mfma_f32_16x16x32_f16(wr[1][kc], bf, acc[1][ns], 0, 0, 0);
                acc[2][ns] = __builtin_amdgcn_mfma_f32_16x16x32_f16(wr[2][kc], bf, acc[2][ns], 0, 0, 0);
                acc[3][ns] = __builtin_amdgcn_mfma_f32_16x16x32_f16(wr[3][kc], bf, acc[3][ns], 0, 0, 0);
            }
        }
        // fused-rational cell update; immediate h write to nxt
        #pragma unroll
        for (int ns = 0; ns < NS; ++ns) {
            union { f16 h[4]; uint2 u; } pk;
            #pragma unroll
            for (int idx = 0; idx < 4; ++idx) {
                float ea = __builtin_amdgcn_exp2f(acc[0][ns][idx] * -K1);
                float ef = __builtin_amdgcn_exp2f(acc[1][ns][idx] * -K1);
                float eg = __builtin_amdgcn_exp2f(acc[2][ns][idx] *  K2);
                float eo = __builtin_amdgcn_exp2f(acc[3][ns][idx] * -K1);
                float a1 = 1.f + ea, a2 = 1.f + ef, a3 = eg + 1.f, a4 = eg - 1.f;
                float t1 = a1 * a3;
                float N1 = fmaf(creg[ns][idx], t1, a4 * a2);
                float cn = N1 * __builtin_amdgcn_rcpf(t1 * a2);
                creg[ns][idx] = cn;
                float cc = fminf(fmaxf(cn, -15.f), 15.f);
                float ec = __builtin_amdgcn_exp2f(cc * K2);
                float hv = (ec - 1.f) * __builtin_amdgcn_rcpf((1.f + eo) * (ec + 1.f));
                pk.h[idx] = (f16)hv;
            }
            *(uint2*)(nxt + (ns * 16 + cl) * 512 + physh * 16 + hoff) = pk.u;
        }
        if (tid < SAMP) {
            union { f16 h[8]; uint4 u; } pk;
            pk.h[0] = (f16)xv0; pk.h[1] = (f16)xv1; pk.h[2] = (f16)xv2;
            pk.h[3] = (f16)xv3; pk.h[4] = (f16)xv4;
            pk.h[5] = (f16)1.f; pk.h[6] = (f16)0.f; pk.h[7] = (f16)0.f;
            int phys = 16 ^ (2 * (tid & 15));
            *(uint4*)(nxt + tid * 512 + phys * 16) = pk.u;
        }
        __syncthreads();   // writes to nxt visible; all reads of cur complete
    }

    // decoder weight fragments + linear head (loaded here to shorten live ranges)
    {
        const f16x8* wp = (const f16x8*)(wfrag + 81920);
        #pragma unroll
        for (int gs = 0; gs < 4; ++gs) {
            #pragma unroll
            for (int kc = 0; kc < 5; ++kc)
                wr[gs][kc] = wp[((w * 4 + gs) * 5 + kc) * 64 + lane];
        }
    }
    float w0r[4], w1r[4];
    #pragma unroll
    for (int idx = 0; idx < 4; ++idx) {
        w0r[idx] = linW[jb + idx];
        w1r[idx] = linW[128 + jb + idx];
    }
    float sc0 = 0.f, sc1 = 0.f, sc2 = 0.f, lb0 = 0.f, lb1 = 0.f;
    if (tid < SAMP) {
        const float* xr = x + (size_t)(s0 + tid) * (TT * II) + 49 * II;
        sc0 = xr[2]; sc1 = xr[3]; sc2 = xr[4];
        lb0 = linB[0]; lb1 = linB[1];
    }

    // ===================== decoder (TT even: td parity continues) ===========
    #pragma unroll 1
    for (int td = 0; td < PRED; ++td) {
        unsigned char* cur = &state[td & 1][0];
        unsigned char* nxt = &state[(td + 1) & 1][0];
        f32x4 acc[4][NS];
        #pragma unroll
        for (int gs = 0; gs < 4; ++gs)
            #pragma unroll
            for (int ns = 0; ns < NS; ++ns) acc[gs][ns] = zero4;

        #pragma unroll
        for (int ns = 0; ns < NS; ++ns) {
            const int srow = ns * 16 + cl;
            #pragma unroll
            for (int kc = 0; kc < 5; ++kc) {
                const int phys = (kc * 4 + q) ^ (2 * cl);
                f16x8 bf = *(const f16x8*)(cur + srow * 512 + phys * 16);
                acc[0][ns] = __builtin_amdgcn_mfma_f32_16x16x32_f16(wr[0][kc], bf, acc[0][ns], 0, 0, 0);
                acc[1][ns] = __builtin_amdgcn_mfma_f32_16x16x32_f16(wr[1][kc], bf, acc[1][ns], 0, 0, 0);
                acc[2][ns] = __builtin_amdgcn_mfma_f32_16x16x32_f16(wr[2][kc], bf, acc[2][ns], 0, 0, 0);
                acc[3][ns] = __builtin_amdgcn_mfma_f32_16x16x32_f16(wr[3][kc], bf, acc[3][ns], 0, 0, 0);
            }
        }
        float p0[NS], p1[NS];
        #pragma unroll
        for (int ns = 0; ns < NS; ++ns) {
            union { f16 h[4]; uint2 u; } pk;
            p0[ns] = 0.f; p1[ns] = 0.f;
            #pragma unroll
            for (int idx = 0; idx < 4; ++idx) {
                float ea = __builtin_amdgcn_exp2f(acc[0][ns][idx] * -K1);
                float ef = __builtin_amdgcn_exp2f(acc[1][ns][idx] * -K1);
                float eg = __builtin_amdgcn_exp2f(acc[2][ns][idx] *  K2);
                float eo = __builtin_amdgcn_exp2f(acc[3][ns][idx] * -K1);
                float a1 = 1.f + ea, a2 = 1.f + ef, a3 = eg + 1.f, a4 = eg - 1.f;
                float t1 = a1 * a3;
                float N1 = fmaf(creg[ns][idx], t1, a4 * a2);
                float cn = N1 * __builtin_amdgcn_rcpf(t1 * a2);
                creg[ns][idx] = cn;
                float cc = fminf(fmaxf(cn, -15.f), 15.f);
                float ec = __builtin_amdgcn_exp2f(cc * K2);
                float hv = (ec - 1.f) * __builtin_amdgcn_rcpf((1.f + eo) * (ec + 1.f));
                p0[ns] = fmaf(hv, w0r[idx], p0[ns]);
                p1[ns] = fmaf(hv, w1r[idx], p1[ns]);
                pk.h[idx] = (f16)hv;
            }
            *(uint2*)(nxt + (ns * 16 + cl) * 512 + physh * 16 + hoff) = pk.u;
        }
        // reduce pred partials over q (lanes l, l^16, l^32, l^48 share sample)
        #pragma unroll
        for (int ns = 0; ns < NS; ++ns) {
            p0[ns] += __shfl_xor(p0[ns], 16);
            p0[ns] += __shfl_xor(p0[ns], 32);
            p1[ns] += __shfl_xor(p1[ns], 16);
            p1[ns] += __shfl_xor(p1[ns], 32);
        }
        if (q == 0) {
            #pragma unroll
            for (int ns = 0; ns < NS; ++ns) {
                predpart[w][ns * 16 + cl][0] = p0[ns];
                predpart[w][ns * 16 + cl][1] = p1[ns];
            }
        }
        __syncthreads();   // h + predpart written; reads of cur complete
        if (tid < SAMP) {
            float a0 = lb0, a1 = lb1;
            #pragma unroll
            for (int ww = 0; ww < 8; ++ww) {
                a0 += predpart[ww][tid][0];
                a1 += predpart[ww][tid][1];
            }
            float2 o2; o2.x = a0; o2.y = a1;
            *(float2*)(out + (size_t)(s0 + tid) * (PRED * 2) + td * 2) = o2;
            union { f16 h[8]; uint4 u; } pk;
            pk.h[0] = (f16)a0; pk.h[1] = (f16)a1;
            pk.h[2] = (f16)sc0; pk.h[3] = (f16)sc1; pk.h[4] = (f16)sc2;
            pk.h[5] = (f16)1.f; pk.h[6] = (f16)0.f; pk.h[7] = (f16)0.f;
            int phys = 16 ^ (2 * (tid & 15));
            *(uint4*)(nxt + tid * 512 + phys * 16) = pk.u;
        }
        __syncthreads();   // dec input chunk visible before next step reads nxt
    }
}

extern "C" void kernel_launch(void* const* d_in, const int* in_sizes, int n_in,
                              void* d_out, int out_size, void* d_ws, size_t ws_size,
                              hipStream_t stream) {
    (void)in_sizes; (void)n_in; (void)out_size; (void)ws_size;
    const float* x    = (const float*)d_in[0];
    const float* eWih = (const float*)d_in[1];
    const float* eWhh = (const float*)d_in[2];
    const float* ebih = (const float*)d_in[3];
    const float* ebhh = (const float*)d_in[4];
    const float* dWih = (const float*)d_in[5];
    const float* dWhh = (const float*)d_in[6];
    const float* dbih = (const float*)d_in[7];
    const float* dbhh = (const float*)d_in[8];
    const float* linW = (const float*)d_in[9];
    const float* linB = (const float*)d_in[10];
    f16* wfrag = (f16*)d_ws;

    prep_weights<<<640, 256, 0, stream>>>(eWih, eWhh, ebih, ebhh,
                                          dWih, dWhh, dbih, dbhh, wfrag);
    lstm_kernel<<<512, 512, 0, stream>>>(x, wfrag, linW, linB, (float*)d_out);
}

// Round 3
// 290.649 us; speedup vs baseline: 3.2098x; 3.2098x over previous
//
#include <hip/hip_runtime.h>
#include <cstdint>

#define TT 50
#define II 5
#define PRED 12

typedef _Float16 f16;
typedef _Float16 f16x8 __attribute__((ext_vector_type(8)));
typedef float f32x4 __attribute__((ext_vector_type(4)));

#define K1 1.4426950408889634f
#define K2 2.8853900817779268f

// fused-rational LSTM cell: 5 exp + 2 rcp (rcp chain: cn needed before ec)
__device__ __forceinline__ float cellact(float xi, float xf, float xg, float xo, float& c) {
    float ea = __builtin_amdgcn_exp2f(xi * -K1);
    float ef = __builtin_amdgcn_exp2f(xf * -K1);
    float eg = __builtin_amdgcn_exp2f(xg *  K2);
    float eo = __builtin_amdgcn_exp2f(xo * -K1);
    float a1 = 1.f + ea, a2 = 1.f + ef, a3 = eg + 1.f, a4 = eg - 1.f;
    float t1 = a1 * a3;
    float cn = fmaf(c, t1, a4 * a2) * __builtin_amdgcn_rcpf(t1 * a2);
    c = cn;
    float cc = fminf(fmaxf(cn, -15.f), 15.f);
    float ec = __builtin_amdgcn_exp2f(cc * K2);
    return (ec - 1.f) * __builtin_amdgcn_rcpf((1.f + eo) * (ec + 1.f));
}

// direct global->register weight fragments (replaces prep kernel).
// lane (w,q,cl) holds A-frag for gate tile (w,gs): A[m=cl][k=q*8+j] of
// Wcat[g][k]: g = gs*128 + w*16 + cl; k<128 -> Whh, 128..132 -> Wih,
// 133 -> bih+bhh, else 0.  k = kc*32 + q*8 + j.
__device__ __forceinline__ void load_weights(const float* __restrict__ Wih, const float* __restrict__ Whh,
                                             const float* __restrict__ bih, const float* __restrict__ bhh,
                                             f16x8 wr[4][5], int w, int cl, int q) {
    #pragma unroll
    for (int gs = 0; gs < 4; ++gs) {
        const int g = gs * 128 + w * 16 + cl;
        const float* row = Whh + g * 128 + q * 8;
        #pragma unroll
        for (int kc = 0; kc < 4; ++kc) {
            float4 a = *(const float4*)(row + kc * 32);
            float4 b = *(const float4*)(row + kc * 32 + 4);
            f16x8 r;
            r[0] = (f16)a.x; r[1] = (f16)a.y; r[2] = (f16)a.z; r[3] = (f16)a.w;
            r[4] = (f16)b.x; r[5] = (f16)b.y; r[6] = (f16)b.z; r[7] = (f16)b.w;
            wr[gs][kc] = r;
        }
        f16x8 r;
        #pragma unroll
        for (int j = 0; j < 8; ++j) {
            int k = 128 + q * 8 + j;
            float v = 0.f;
            if (k < 133)       v = Wih[g * 5 + (k - 128)];
            else if (k == 133) v = bih[g] + bhh[g];
            r[j] = (f16)v;
        }
        wr[gs][4] = r;
    }
}

__device__ __forceinline__ void do_mfma(const unsigned char* sb, const f16x8 wr[4][5],
                                        f32x4 acc[4][2], int cl, int q) {
    #pragma unroll
    for (int ns = 0; ns < 2; ++ns) {
        const int srow = ns * 16 + cl;
        #pragma unroll
        for (int kc = 0; kc < 5; ++kc) {
            const int phys = (kc * 4 + q) ^ (2 * cl);
            f16x8 bf = *(const f16x8*)(sb + srow * 512 + phys * 16);
            acc[0][ns] = __builtin_amdgcn_mfma_f32_16x16x32_f16(wr[0][kc], bf, acc[0][ns], 0, 0, 0);
            acc[1][ns] = __builtin_amdgcn_mfma_f32_16x16x32_f16(wr[1][kc], bf, acc[1][ns], 0, 0, 0);
            acc[2][ns] = __builtin_amdgcn_mfma_f32_16x16x32_f16(wr[2][kc], bf, acc[2][ns], 0, 0, 0);
            acc[3][ns] = __builtin_amdgcn_mfma_f32_16x16x32_f16(wr[3][kc], bf, acc[3][ns], 0, 0, 0);
        }
    }
}

__device__ __forceinline__ void do_act(f32x4 acc[4][2], float creg[2][4], unsigned char* dst,
                                       int cl, int physh, int hoff) {
    #pragma unroll
    for (int ns = 0; ns < 2; ++ns) {
        union { f16 h[4]; uint2 u; } pk;
        #pragma unroll
        for (int idx = 0; idx < 4; ++idx)
            pk.h[idx] = (f16)cellact(acc[0][ns][idx], acc[1][ns][idx], acc[2][ns][idx],
                                     acc[3][ns][idx], creg[ns][idx]);
        *(uint2*)(dst + (ns * 16 + cl) * 512 + physh * 16 + hoff) = pk.u;
    }
}

__device__ __forceinline__ void do_act_dec(f32x4 acc[4][2], float creg[2][4], unsigned char* dst,
                                           int cl, int physh, int hoff,
                                           const float w0r[4], const float w1r[4],
                                           float p0[2], float p1[2]) {
    #pragma unroll
    for (int ns = 0; ns < 2; ++ns) {
        union { f16 h[4]; uint2 u; } pk;
        p0[ns] = 0.f; p1[ns] = 0.f;
        #pragma unroll
        for (int idx = 0; idx < 4; ++idx) {
            float hv = cellact(acc[0][ns][idx], acc[1][ns][idx], acc[2][ns][idx],
                               acc[3][ns][idx], creg[ns][idx]);
            p0[ns] = fmaf(hv, w0r[idx], p0[ns]);
            p1[ns] = fmaf(hv, w1r[idx], p1[ns]);
            pk.h[idx] = (f16)hv;
        }
        *(uint2*)(dst + (ns * 16 + cl) * 512 + physh * 16 + hoff) = pk.u;
    }
}

// input chunk (logical chunk 16): [x0..x4, 1, 0, 0]
__device__ __forceinline__ void write_x5(unsigned char* sb, int sl,
                                         float v0, float v1, float v2, float v3, float v4) {
    union { f16 h[8]; uint4 u; } pk;
    pk.h[0] = (f16)v0; pk.h[1] = (f16)v1; pk.h[2] = (f16)v2;
    pk.h[3] = (f16)v3; pk.h[4] = (f16)v4;
    pk.h[5] = (f16)1.f; pk.h[6] = (f16)0.f; pk.h[7] = (f16)0.f;
    int phys = 16 ^ (2 * (sl & 15));
    *(uint4*)(sb + sl * 512 + phys * 16) = pk.u;
}

// ---------------- persistent two-stream LSTM kernel ----------------
// 256 blocks x 512 threads; 64 samples/block = groups A (0..31) + B (32..63).
// Encoder pipeline per t: [mfma_A(t), act_B(t-1)] barrier [mfma_B(t), act_A(t)] barrier
// -> matrix pipe of one group overlaps trans burst of the other.
__global__ __launch_bounds__(512, 2)
void lstm_kernel(const float* __restrict__ x,
                 const float* __restrict__ eWih, const float* __restrict__ eWhh,
                 const float* __restrict__ ebih, const float* __restrict__ ebhh,
                 const float* __restrict__ dWih, const float* __restrict__ dWhh,
                 const float* __restrict__ dbih, const float* __restrict__ dbhh,
                 const float* __restrict__ linW, const float* __restrict__ linB,
                 float* __restrict__ out) {
    __shared__ __align__(16) unsigned char stateA[2][32 * 512];
    __shared__ __align__(16) unsigned char stateB[2][32 * 512];
    __shared__ float ppA[8][32][2], ppB[8][32][2];

    const int tid  = threadIdx.x;
    const int lane = tid & 63;
    const int w    = tid >> 6;
    const int q    = lane >> 4;
    const int cl   = lane & 15;
    const int s0   = blockIdx.x * 64;
    const int jb   = w * 16 + q * 4;
    const int physh = ((jb >> 3) ^ (2 * cl)) & 31;
    const int hoff  = (jb & 7) * 2;

    f16x8 wr[4][5];
    load_weights(eWih, eWhh, ebih, ebhh, wr, w, cl, q);

    // zero all 64 KB of state (h0 = 0 + zero pad chunks 17..19)
    {
        uint4 z{0, 0, 0, 0};
        uint4* pa = (uint4*)&stateA[0][0];
        uint4* pb = (uint4*)&stateB[0][0];
        #pragma unroll
        for (int r = 0; r < 4; ++r) { pa[tid + r * 512] = z; pb[tid + r * 512] = z; }
    }
    float cregA[2][4], cregB[2][4];
    #pragma unroll
    for (int a = 0; a < 2; ++a)
        #pragma unroll
        for (int b = 0; b < 4; ++b) { cregA[a][b] = 0.f; cregB[a][b] = 0.f; }
    f32x4 accA[4][2], accB[4][2];
    const f32x4 z4 = {0.f, 0.f, 0.f, 0.f};

    __syncthreads();
    if (tid < 32) {   // x_A(0); x_B(0) is written by iter-0 phase 2
        const float* xr = x + (size_t)(s0 + tid) * (TT * II);
        write_x5(stateA[0], tid, xr[0], xr[1], xr[2], xr[3], xr[4]);
    }
    __syncthreads();

    // ===================== encoder, two-stream pipelined =====================
    #pragma unroll 1
    for (int t = 0; t < TT; ++t) {
        unsigned char* curA = stateA[t & 1];
        unsigned char* nxtA = stateA[(t + 1) & 1];
        unsigned char* curB = stateB[t & 1];
        // x loads: tid<32 -> x_A(t+1) (clamped: t=49 re-reads x_49 = dec_in0),
        //          tid 32..63 -> x_B(t)
        float xv0 = 0, xv1 = 0, xv2 = 0, xv3 = 0, xv4 = 0;
        if (tid < 64) {
            int tl = (tid < 32) ? ((t < TT - 1) ? t + 1 : TT - 1) : t;
            const float* xr = x + (size_t)(s0 + tid) * (TT * II) + tl * II;
            xv0 = xr[0]; xv1 = xr[1]; xv2 = xr[2]; xv3 = xr[3]; xv4 = xr[4];
        }
        // phase 1: MFMA_A(t)
        #pragma unroll
        for (int gs = 0; gs < 4; ++gs) { accA[gs][0] = z4; accA[gs][1] = z4; }
        do_mfma(curA, wr, accA, cl, q);
        // phase 2: act_B(t-1) -> h_B into stateB[t&1]; x_B(t) -> stateB[t&1]
        if (t > 0) do_act(accB, cregB, curB, cl, physh, hoff);
        if (tid >= 32 && tid < 64) write_x5(curB, tid - 32, xv0, xv1, xv2, xv3, xv4);
        __syncthreads();
        // phase 4: MFMA_B(t)
        #pragma unroll
        for (int gs = 0; gs < 4; ++gs) { accB[gs][0] = z4; accB[gs][1] = z4; }
        do_mfma(curB, wr, accB, cl, q);
        // phase 5: act_A(t) -> h_A + x_A(t+1) into stateA[(t+1)&1]
        do_act(accA, cregA, nxtA, cl, physh, hoff);
        if (tid < 32) write_x5(nxtA, tid, xv0, xv1, xv2, xv3, xv4);
        __syncthreads();
    }
    // epilogue: act_B(49) + B's decoder input -> stateB[0]
    do_act(accB, cregB, stateB[0], cl, physh, hoff);
    if (tid >= 32 && tid < 64) {
        const float* xr = x + (size_t)(s0 + tid) * (TT * II) + (TT - 1) * II;
        write_x5(stateB[0], tid - 32, xr[0], xr[1], xr[2], xr[3], xr[4]);
    }
    __syncthreads();

    // decoder weights + linear head + static context
    load_weights(dWih, dWhh, dbih, dbhh, wr, w, cl, q);
    float w0r[4], w1r[4];
    #pragma unroll
    for (int idx = 0; idx < 4; ++idx) {
        w0r[idx] = linW[jb + idx];
        w1r[idx] = linW[128 + jb + idx];
    }
    float sc0 = 0, sc1 = 0, sc2 = 0, lb0 = 0, lb1 = 0;
    if (tid < 64) {
        const float* xr = x + (size_t)(s0 + tid) * (TT * II) + (TT - 1) * II;
        sc0 = xr[2]; sc1 = xr[3]; sc2 = xr[4];
        lb0 = linB[0]; lb1 = linB[1];
    }

    // ===================== decoder, flat both groups =====================
    #pragma unroll 1
    for (int dt = 0; dt < PRED; ++dt) {
        int t = TT + dt;   // TT even -> dt=0 reads buf 0 (written above)
        unsigned char* curA = stateA[t & 1]; unsigned char* nxtA = stateA[(t + 1) & 1];
        unsigned char* curB = stateB[t & 1]; unsigned char* nxtB = stateB[(t + 1) & 1];
        #pragma unroll
        for (int gs = 0; gs < 4; ++gs) {
            accA[gs][0] = z4; accA[gs][1] = z4;
            accB[gs][0] = z4; accB[gs][1] = z4;
        }
        do_mfma(curA, wr, accA, cl, q);
        do_mfma(curB, wr, accB, cl, q);
        float p0A[2], p1A[2], p0B[2], p1B[2];
        do_act_dec(accA, cregA, nxtA, cl, physh, hoff, w0r, w1r, p0A, p1A);
        do_act_dec(accB, cregB, nxtB, cl, physh, hoff, w0r, w1r, p0B, p1B);
        // reduce pred partials over q (lanes l, l^16, l^32, l^48 share sample)
        #pragma unroll
        for (int ns = 0; ns < 2; ++ns) {
            p0A[ns] += __shfl_xor(p0A[ns], 16); p0A[ns] += __shfl_xor(p0A[ns], 32);
            p1A[ns] += __shfl_xor(p1A[ns], 16); p1A[ns] += __shfl_xor(p1A[ns], 32);
            p0B[ns] += __shfl_xor(p0B[ns], 16); p0B[ns] += __shfl_xor(p0B[ns], 32);
            p1B[ns] += __shfl_xor(p1B[ns], 16); p1B[ns] += __shfl_xor(p1B[ns], 32);
        }
        if (q == 0) {
            #pragma unroll
            for (int ns = 0; ns < 2; ++ns) {
                ppA[w][ns * 16 + cl][0] = p0A[ns]; ppA[w][ns * 16 + cl][1] = p1A[ns];
                ppB[w][ns * 16 + cl][0] = p0B[ns]; ppB[w][ns * 16 + cl][1] = p1B[ns];
            }
        }
        __syncthreads();
        if (tid < 64) {
            int sl = tid & 31;
            float (*pp)[32][2] = (tid < 32) ? ppA : ppB;
            float a0 = lb0, a1 = lb1;
            #pragma unroll
            for (int ww = 0; ww < 8; ++ww) { a0 += pp[ww][sl][0]; a1 += pp[ww][sl][1]; }
            float2 o2; o2.x = a0; o2.y = a1;
            *(float2*)(out + (size_t)(s0 + tid) * (PRED * 2) + dt * 2) = o2;
            write_x5((tid < 32) ? nxtA : nxtB, sl, a0, a1, sc0, sc1, sc2);
        }
        __syncthreads();
    }
}

extern "C" void kernel_launch(void* const* d_in, const int* in_sizes, int n_in,
                              void* d_out, int out_size, void* d_ws, size_t ws_size,
                              hipStream_t stream) {
    (void)in_sizes; (void)n_in; (void)out_size; (void)d_ws; (void)ws_size;
    const float* x    = (const float*)d_in[0];
    const float* eWih = (const float*)d_in[1];
    const float* eWhh = (const float*)d_in[2];
    const float* ebih = (const float*)d_in[3];
    const float* ebhh = (const float*)d_in[4];
    const float* dWih = (const float*)d_in[5];
    const float* dWhh = (const float*)d_in[6];
    const float* dbih = (const float*)d_in[7];
    const float* dbhh = (const float*)d_in[8];
    const float* linW = (const float*)d_in[9];
    const float* linB = (const float*)d_in[10];

    lstm_kernel<<<256, 512, 0, stream>>>(x, eWih, eWhh, ebih, ebhh,
                                         dWih, dWhh, dbih, dbhh,
                                         linW, linB, (float*)d_out);
}

// Round 4
// 288.974 us; speedup vs baseline: 3.2284x; 1.0058x over previous
//
#include <hip/hip_runtime.h>
#include <cstdint>

#define TT 50
#define II 5
#define PRED 12

typedef _Float16 f16;
typedef _Float16 f16x8 __attribute__((ext_vector_type(8)));
typedef float f32x4 __attribute__((ext_vector_type(4)));

#define K1 1.4426950408889634f
#define K2 2.8853900817779268f

// fused-rational LSTM cell: 5 exp + 2 rcp
__device__ __forceinline__ float cellact(float xi, float xf, float xg, float xo, float& c) {
    float ea = __builtin_amdgcn_exp2f(xi * -K1);
    float ef = __builtin_amdgcn_exp2f(xf * -K1);
    float eg = __builtin_amdgcn_exp2f(xg *  K2);
    float eo = __builtin_amdgcn_exp2f(xo * -K1);
    float a1 = 1.f + ea, a2 = 1.f + ef, a3 = eg + 1.f, a4 = eg - 1.f;
    float t1 = a1 * a3;
    float cn = fmaf(c, t1, a4 * a2) * __builtin_amdgcn_rcpf(t1 * a2);
    c = cn;
    float cc = fminf(fmaxf(cn, -15.f), 15.f);
    float ec = __builtin_amdgcn_exp2f(cc * K2);
    return (ec - 1.f) * __builtin_amdgcn_rcpf((1.f + eo) * (ec + 1.f));
}

// forced interleave: thread 40 MFMAs through the activation burst
__device__ __forceinline__ void sched_enc() {
    #pragma unroll
    for (int i = 0; i < 8; ++i) {
        __builtin_amdgcn_sched_group_barrier(0x100, 2, 0);  // DS read
        __builtin_amdgcn_sched_group_barrier(0x008, 5, 0);  // MFMA
        __builtin_amdgcn_sched_group_barrier(0x400, 7, 0);  // TRANS
        __builtin_amdgcn_sched_group_barrier(0x002, 20, 0); // VALU
    }
}
__device__ __forceinline__ void sched_dec() {
    #pragma unroll
    for (int i = 0; i < 16; ++i) {
        __builtin_amdgcn_sched_group_barrier(0x100, 2, 0);
        __builtin_amdgcn_sched_group_barrier(0x008, 5, 0);
        __builtin_amdgcn_sched_group_barrier(0x400, 7, 0);
        __builtin_amdgcn_sched_group_barrier(0x002, 20, 0);
    }
}

// direct global->register weight fragments.
// lane (w,q,cl) holds A-frag for gate tile (w,gs): A[m=cl][k=q*8+j] of
// Wcat[g][k]: g = gs*128 + w*16 + cl; k<128 -> Whh, 128..132 -> Wih,
// 133 -> bih+bhh, else 0.  k = kc*32 + q*8 + j.
__device__ __forceinline__ void load_weights(const float* __restrict__ Wih, const float* __restrict__ Whh,
                                             const float* __restrict__ bih, const float* __restrict__ bhh,
                                             f16x8 wr[4][5], int w, int cl, int q) {
    #pragma unroll
    for (int gs = 0; gs < 4; ++gs) {
        const int g = gs * 128 + w * 16 + cl;
        const float* row = Whh + g * 128 + q * 8;
        #pragma unroll
        for (int kc = 0; kc < 4; ++kc) {
            float4 a = *(const float4*)(row + kc * 32);
            float4 b = *(const float4*)(row + kc * 32 + 4);
            f16x8 r;
            r[0] = (f16)a.x; r[1] = (f16)a.y; r[2] = (f16)a.z; r[3] = (f16)a.w;
            r[4] = (f16)b.x; r[5] = (f16)b.y; r[6] = (f16)b.z; r[7] = (f16)b.w;
            wr[gs][kc] = r;
        }
        f16x8 r;
        #pragma unroll
        for (int j = 0; j < 8; ++j) {
            int k = 128 + q * 8 + j;
            float v = 0.f;
            if (k < 133)       v = Wih[g * 5 + (k - 128)];
            else if (k == 133) v = bih[g] + bhh[g];
            r[j] = (f16)v;
        }
        wr[gs][4] = r;
    }
}

__device__ __forceinline__ void do_mfma(const unsigned char* sb, const f16x8 wr[4][5],
                                        f32x4 acc[4][2], int cl, int q) {
    #pragma unroll
    for (int ns = 0; ns < 2; ++ns) {
        const int srow = ns * 16 + cl;
        #pragma unroll
        for (int kc = 0; kc < 5; ++kc) {
            const int phys = (kc * 4 + q) ^ (2 * cl);
            f16x8 bf = *(const f16x8*)(sb + srow * 512 + phys * 16);
            acc[0][ns] = __builtin_amdgcn_mfma_f32_16x16x32_f16(wr[0][kc], bf, acc[0][ns], 0, 0, 0);
            acc[1][ns] = __builtin_amdgcn_mfma_f32_16x16x32_f16(wr[1][kc], bf, acc[1][ns], 0, 0, 0);
            acc[2][ns] = __builtin_amdgcn_mfma_f32_16x16x32_f16(wr[2][kc], bf, acc[2][ns], 0, 0, 0);
            acc[3][ns] = __builtin_amdgcn_mfma_f32_16x16x32_f16(wr[3][kc], bf, acc[3][ns], 0, 0, 0);
        }
    }
}

__device__ __forceinline__ void do_act(f32x4 acc[4][2], float creg[2][4], unsigned char* dst,
                                       int cl, int physh, int hoff) {
    #pragma unroll
    for (int ns = 0; ns < 2; ++ns) {
        union { f16 h[4]; uint2 u; } pk;
        #pragma unroll
        for (int idx = 0; idx < 4; ++idx)
            pk.h[idx] = (f16)cellact(acc[0][ns][idx], acc[1][ns][idx], acc[2][ns][idx],
                                     acc[3][ns][idx], creg[ns][idx]);
        *(uint2*)(dst + (ns * 16 + cl) * 512 + physh * 16 + hoff) = pk.u;
    }
}

__device__ __forceinline__ void do_act_dec(f32x4 acc[4][2], float creg[2][4], unsigned char* dst,
                                           int cl, int physh, int hoff,
                                           const float w0r[4], const float w1r[4],
                                           float p0[2], float p1[2]) {
    #pragma unroll
    for (int ns = 0; ns < 2; ++ns) {
        union { f16 h[4]; uint2 u; } pk;
        p0[ns] = 0.f; p1[ns] = 0.f;
        #pragma unroll
        for (int idx = 0; idx < 4; ++idx) {
            float hv = cellact(acc[0][ns][idx], acc[1][ns][idx], acc[2][ns][idx],
                               acc[3][ns][idx], creg[ns][idx]);
            p0[ns] = fmaf(hv, w0r[idx], p0[ns]);
            p1[ns] = fmaf(hv, w1r[idx], p1[ns]);
            pk.h[idx] = (f16)hv;
        }
        *(uint2*)(dst + (ns * 16 + cl) * 512 + physh * 16 + hoff) = pk.u;
    }
}

// input chunk (logical chunk 16): [x0..x4, 1, 0, 0]
__device__ __forceinline__ void write_x5(unsigned char* sb, int sl,
                                         float v0, float v1, float v2, float v3, float v4) {
    union { f16 h[8]; uint4 u; } pk;
    pk.h[0] = (f16)v0; pk.h[1] = (f16)v1; pk.h[2] = (f16)v2;
    pk.h[3] = (f16)v3; pk.h[4] = (f16)v4;
    pk.h[5] = (f16)1.f; pk.h[6] = (f16)0.f; pk.h[7] = (f16)0.f;
    int phys = 16 ^ (2 * (sl & 15));
    *(uint4*)(sb + sl * 512 + phys * 16) = pk.u;
}

// ---------------- persistent two-stream LSTM kernel ----------------
// 256 blocks x 512 threads; groups A (samples 0..31) + B (32..63).
// Every interval pairs mfma(one group) with act(other group, PREVIOUS
// interval's accumulators) -> fully independent -> sched_group_barrier
// interleaves them so matrix pipe hides under the trans burst.
// Interval steady state:  [mfma_B(t) | act_A(t)]  [mfma_A(t+1) | act_B(t)]
__global__ __launch_bounds__(512, 2)
void lstm_kernel(const float* __restrict__ x,
                 const float* __restrict__ eWih, const float* __restrict__ eWhh,
                 const float* __restrict__ ebih, const float* __restrict__ ebhh,
                 const float* __restrict__ dWih, const float* __restrict__ dWhh,
                 const float* __restrict__ dbih, const float* __restrict__ dbhh,
                 const float* __restrict__ linW, const float* __restrict__ linB,
                 float* __restrict__ out) {
    __shared__ __align__(16) unsigned char stateA[2][32 * 512];
    __shared__ __align__(16) unsigned char stateB[2][32 * 512];
    __shared__ float ppA[8][32][2], ppB[8][32][2];

    const int tid  = threadIdx.x;
    const int lane = tid & 63;
    const int w    = tid >> 6;
    const int q    = lane >> 4;
    const int cl   = lane & 15;
    const int s0   = blockIdx.x * 64;
    const int jb   = w * 16 + q * 4;
    const int physh = ((jb >> 3) ^ (2 * cl)) & 31;
    const int hoff  = (jb & 7) * 2;

    f16x8 wr[4][5];
    load_weights(eWih, eWhh, ebih, ebhh, wr, w, cl, q);

    // zero all state (h0 = 0 + zero pad chunks 17..19)
    {
        uint4 z{0, 0, 0, 0};
        uint4* pa = (uint4*)&stateA[0][0];
        uint4* pb = (uint4*)&stateB[0][0];
        #pragma unroll
        for (int r = 0; r < 4; ++r) { pa[tid + r * 512] = z; pb[tid + r * 512] = z; }
    }
    float cregA[2][4], cregB[2][4];
    #pragma unroll
    for (int a = 0; a < 2; ++a)
        #pragma unroll
        for (int b = 0; b < 4; ++b) { cregA[a][b] = 0.f; cregB[a][b] = 0.f; }
    f32x4 accA[4][2], accB[4][2];
    const f32x4 z4 = {0.f, 0.f, 0.f, 0.f};

    __syncthreads();
    if (tid < 64) {   // x_A(0) -> stateA[0], x_B(0) -> stateB[0]
        const float* xr = x + (size_t)(s0 + tid) * (TT * II);
        write_x5((tid < 32) ? stateA[0] : stateB[0], tid & 31,
                 xr[0], xr[1], xr[2], xr[3], xr[4]);
    }
    __syncthreads();

    // prologue: mfma_A(0)
    #pragma unroll
    for (int gs = 0; gs < 4; ++gs) { accA[gs][0] = z4; accA[gs][1] = z4; }
    do_mfma(stateA[0], wr, accA, cl, q);
    __syncthreads();

    // ================= encoder steady state, t = 0..48 =================
    #pragma unroll 1
    for (int t = 0; t < TT - 1; ++t) {
        // x(t+1) for both groups
        float xv0 = 0, xv1 = 0, xv2 = 0, xv3 = 0, xv4 = 0;
        if (tid < 64) {
            const float* xr = x + (size_t)(s0 + tid) * (TT * II) + (t + 1) * II;
            xv0 = xr[0]; xv1 = xr[1]; xv2 = xr[2]; xv3 = xr[3]; xv4 = xr[4];
        }
        unsigned char* curB = stateB[t & 1];
        unsigned char* nxtA = stateA[(t + 1) & 1];
        unsigned char* nxtB = stateB[(t + 1) & 1];
        // I2(t): mfma_B(t) || act_A(t)  (accA from previous interval)
        #pragma unroll
        for (int gs = 0; gs < 4; ++gs) { accB[gs][0] = z4; accB[gs][1] = z4; }
        do_mfma(curB, wr, accB, cl, q);
        do_act(accA, cregA, nxtA, cl, physh, hoff);
        if (tid < 32) write_x5(nxtA, tid, xv0, xv1, xv2, xv3, xv4);
        sched_enc();
        __syncthreads();
        // I1(t+1): mfma_A(t+1) || act_B(t)
        #pragma unroll
        for (int gs = 0; gs < 4; ++gs) { accA[gs][0] = z4; accA[gs][1] = z4; }
        do_mfma(nxtA, wr, accA, cl, q);
        do_act(accB, cregB, nxtB, cl, physh, hoff);
        if (tid >= 32 && tid < 64) write_x5(nxtB, tid - 32, xv0, xv1, xv2, xv3, xv4);
        sched_enc();
        __syncthreads();
    }
    // tail: I2(49): mfma_B(49) || act_A(49); then act_B(49).
    // decoder input = x_49 (dec_in0 = [x49_vel, x49_static] = x_49 exactly)
    float xv0 = 0, xv1 = 0, xv2 = 0, xv3 = 0, xv4 = 0;
    if (tid < 64) {
        const float* xr = x + (size_t)(s0 + tid) * (TT * II) + (TT - 1) * II;
        xv0 = xr[0]; xv1 = xr[1]; xv2 = xr[2]; xv3 = xr[3]; xv4 = xr[4];
    }
    #pragma unroll
    for (int gs = 0; gs < 4; ++gs) { accB[gs][0] = z4; accB[gs][1] = z4; }
    do_mfma(stateB[1], wr, accB, cl, q);             // curB = stateB[49&1]
    do_act(accA, cregA, stateA[0], cl, physh, hoff); // h_A(49) -> stateA[50&1=0]
    if (tid < 32) write_x5(stateA[0], tid, xv0, xv1, xv2, xv3, xv4);
    sched_enc();
    __syncthreads();
    do_act(accB, cregB, stateB[0], cl, physh, hoff); // h_B(49) -> stateB[0]
    if (tid >= 32 && tid < 64) write_x5(stateB[0], tid - 32, xv0, xv1, xv2, xv3, xv4);
    __syncthreads();

    // decoder weights + linear head + static context
    load_weights(dWih, dWhh, dbih, dbhh, wr, w, cl, q);
    float w0r[4], w1r[4];
    #pragma unroll
    for (int idx = 0; idx < 4; ++idx) {
        w0r[idx] = linW[jb + idx];
        w1r[idx] = linW[128 + jb + idx];
    }
    float sc0 = xv2, sc1 = xv3, sc2 = xv4, lb0 = 0, lb1 = 0;
    if (tid < 64) { lb0 = linB[0]; lb1 = linB[1]; }

    // ===================== decoder, flat both groups =====================
    #pragma unroll 1
    for (int dt = 0; dt < PRED; ++dt) {
        int t = TT + dt;   // TT even -> dt=0 reads buf 0 (written above)
        unsigned char* curA = stateA[t & 1]; unsigned char* nxtA = stateA[(t + 1) & 1];
        unsigned char* curB = stateB[t & 1]; unsigned char* nxtB = stateB[(t + 1) & 1];
        #pragma unroll
        for (int gs = 0; gs < 4; ++gs) {
            accA[gs][0] = z4; accA[gs][1] = z4;
            accB[gs][0] = z4; accB[gs][1] = z4;
        }
        do_mfma(curA, wr, accA, cl, q);
        do_mfma(curB, wr, accB, cl, q);
        float p0A[2], p1A[2], p0B[2], p1B[2];
        do_act_dec(accA, cregA, nxtA, cl, physh, hoff, w0r, w1r, p0A, p1A);
        do_act_dec(accB, cregB, nxtB, cl, physh, hoff, w0r, w1r, p0B, p1B);
        sched_dec();
        // reduce pred partials over q (lanes l, l^16, l^32, l^48 share sample)
        #pragma unroll
        for (int ns = 0; ns < 2; ++ns) {
            p0A[ns] += __shfl_xor(p0A[ns], 16); p0A[ns] += __shfl_xor(p0A[ns], 32);
            p1A[ns] += __shfl_xor(p1A[ns], 16); p1A[ns] += __shfl_xor(p1A[ns], 32);
            p0B[ns] += __shfl_xor(p0B[ns], 16); p0B[ns] += __shfl_xor(p0B[ns], 32);
            p1B[ns] += __shfl_xor(p1B[ns], 16); p1B[ns] += __shfl_xor(p1B[ns], 32);
        }
        if (q == 0) {
            #pragma unroll
            for (int ns = 0; ns < 2; ++ns) {
                ppA[w][ns * 16 + cl][0] = p0A[ns]; ppA[w][ns * 16 + cl][1] = p1A[ns];
                ppB[w][ns * 16 + cl][0] = p0B[ns]; ppB[w][ns * 16 + cl][1] = p1B[ns];
            }
        }
        __syncthreads();
        if (tid < 64) {
            int sl = tid & 31;
            float (*pp)[32][2] = (tid < 32) ? ppA : ppB;
            float a0 = lb0, a1 = lb1;
            #pragma unroll
            for (int ww = 0; ww < 8; ++ww) { a0 += pp[ww][sl][0]; a1 += pp[ww][sl][1]; }
            float2 o2; o2.x = a0; o2.y = a1;
            *(float2*)(out + (size_t)(s0 + tid) * (PRED * 2) + dt * 2) = o2;
            write_x5((tid < 32) ? nxtA : nxtB, sl, a0, a1, sc0, sc1, sc2);
        }
        __syncthreads();
    }
}

extern "C" void kernel_launch(void* const* d_in, const int* in_sizes, int n_in,
                              void* d_out, int out_size, void* d_ws, size_t ws_size,
                              hipStream_t stream) {
    (void)in_sizes; (void)n_in; (void)out_size; (void)d_ws; (void)ws_size;
    const float* x    = (const float*)d_in[0];
    const float* eWih = (const float*)d_in[1];
    const float* eWhh = (const float*)d_in[2];
    const float* ebih = (const float*)d_in[3];
    const float* ebhh = (const float*)d_in[4];
    const float* dWih = (const float*)d_in[5];
    const float* dWhh = (const float*)d_in[6];
    const float* dbih = (const float*)d_in[7];
    const float* dbhh = (const float*)d_in[8];
    const float* linW = (const float*)d_in[9];
    const float* linB = (const float*)d_in[10];

    lstm_kernel<<<256, 512, 0, stream>>>(x, eWih, eWhh, ebih, ebhh,
                                         dWih, dWhh, dbih, dbhh,
                                         linW, linB, (float*)d_out);
}